// Round 1
// baseline (5777.576 us; speedup 1.0000x reference)
//
#include <hip/hip_runtime.h>
#include <math.h>

#define NB 16
#define NE 4
#define THRESH 0.2f

// ---------------- repack kernels ----------------
// w2[(c*9+ij)*EO + eo] = ew[((eo)*C + c)*9 + ij]
__global__ void repack_w_kernel(const float* __restrict__ ew, float* __restrict__ w2,
                                int EO, int C) {
    int n = EO * C * 9;
    for (int i = blockIdx.x * blockDim.x + threadIdx.x; i < n; i += gridDim.x * blockDim.x) {
        int eo = i / (C * 9);
        int r  = i % (C * 9);
        w2[(size_t)r * EO + eo] = ew[i];
    }
}

// fwT[c*Co + o] = fw[o*Co + c]
__global__ void repack_fin_kernel(const float* __restrict__ fw, float* __restrict__ fwT, int Co) {
    int n = Co * Co;
    for (int i = blockIdx.x * blockDim.x + threadIdx.x; i < n; i += gridDim.x * blockDim.x) {
        int o = i / Co, c = i % Co;
        fwT[c * Co + o] = fw[i];
    }
}

// ---------------- router: pooled conv -> softmax scores ----------------
// mean over 8x8 of 3x3 pad-1 conv == (1/64) * sum_{c,i,j} w[o,c,i,j]*S[c,i,j] + bias,
// where S[i][j] are clipped-window sums derived from total/row/col sums + corners.
template<int CIN, int C>
__global__ __launch_bounds__(256) void router_kernel(
    const float* __restrict__ X, const float* __restrict__ pw, const float* __restrict__ pb,
    const float* __restrict__ rw, const float* __restrict__ rb,
    float* __restrict__ scores, int H, int W, int nP)
{
    __shared__ float S[4][C * 9 + 8];
    const int wv = threadIdx.x >> 6;
    const int lane = threadIdx.x & 63;
    const int bp = blockIdx.x * 4 + wv;
    const int P = nP * nP;
    const int b = bp / P, pi = bp % P;
    const int py = pi / nP, px = pi % nP;
    const int h = lane >> 3, w = lane & 7;
    const int gy = py * 8 + h, gx = px * 8 + w;
    float* Sw = S[wv];
    for (int c = 0; c < C; ++c) {
        float v;
        if (c < CIN) {
            v = X[(((size_t)b * CIN + c) * H + gy) * W + gx];
        } else {
            float t = (c == CIN || c == CIN + 2) ? gx * (1.f / (W - 1)) : gy * (1.f / (H - 1));
            v = (c >= CIN + 2) ? sinf(3.14159265358979323846f * t) : t;
        }
        float r = v;                       // row sums: lanes grouped by h (8 consecutive)
        r += __shfl_xor(r, 1); r += __shfl_xor(r, 2); r += __shfl_xor(r, 4);
        float cc = v;                      // col sums: lanes grouped by w
        cc += __shfl_xor(cc, 8); cc += __shfl_xor(cc, 16); cc += __shfl_xor(cc, 32);
        float T = r;
        T += __shfl_xor(T, 8); T += __shfl_xor(T, 16); T += __shfl_xor(T, 32);
        float R0 = __shfl(r, 0), R7 = __shfl(r, 56);
        float C0 = __shfl(cc, 0), C7 = __shfl(cc, 7);
        float x00 = __shfl(v, 0), x07 = __shfl(v, 7);
        float x70 = __shfl(v, 56), x77 = __shfl(v, 63);
        if (lane < 9) {
            int i = lane / 3, j = lane % 3;
            // rows(i=0)={0..6} (excl row7), rows(2)={1..7} (excl row0); cols similarly
            float s = T;
            if (i == 0) s -= R7; else if (i == 2) s -= R0;
            if (j == 0) s -= C7; else if (j == 2) s -= C0;
            if (i == 0 && j == 0) s += x77;
            else if (i == 0 && j == 2) s += x70;
            else if (i == 2 && j == 0) s += x07;
            else if (i == 2 && j == 2) s += x00;
            Sw[c * 9 + lane] = s;
        }
    }
    __syncthreads();
    if (lane < 8) {
        const int o = lane;
        float acc = 0.f;
        for (int c = 0; c < C; ++c) {
            #pragma unroll
            for (int ij = 0; ij < 9; ++ij)
                acc += pw[(o * C + c) * 9 + ij] * Sw[c * 9 + ij];
        }
        Sw[C * 9 + o] = acc * (1.f / 64.f) + pb[o];
    }
    __syncthreads();
    if (lane == 0) {
        float lg[NE];
        float m = -1e30f;
        #pragma unroll
        for (int e = 0; e < NE; ++e) {
            float a = rb[e];
            #pragma unroll
            for (int o = 0; o < 8; ++o) a += Sw[C * 9 + o] * rw[e * 8 + o];
            lg[e] = a;
            m = fmaxf(m, a);
        }
        float ssum = 0.f;
        #pragma unroll
        for (int e = 0; e < NE; ++e) { lg[e] = __expf(lg[e] - m); ssum += lg[e]; }
        float inv = 1.f / ssum;
        #pragma unroll
        for (int e = 0; e < NE; ++e) scores[bp * NE + e] = lg[e] * inv;
    }
}

// ---------------- gate: per-expert global max > THRESH ----------------
__global__ __launch_bounds__(256) void gate_kernel(const float* __restrict__ scores, int BP,
                                                   float* __restrict__ gate)
{
    __shared__ float sm[4][NE];
    float m[NE] = {-1e30f, -1e30f, -1e30f, -1e30f};
    for (int i = threadIdx.x; i < BP; i += 256) {
        #pragma unroll
        for (int e = 0; e < NE; ++e) m[e] = fmaxf(m[e], scores[i * NE + e]);
    }
    #pragma unroll
    for (int e = 0; e < NE; ++e) {
        float v = m[e];
        for (int o = 32; o; o >>= 1) v = fmaxf(v, __shfl_xor(v, o));
        m[e] = v;
    }
    int wv = threadIdx.x >> 6, lane = threadIdx.x & 63;
    if (lane == 0) {
        #pragma unroll
        for (int e = 0; e < NE; ++e) sm[wv][e] = m[e];
    }
    __syncthreads();
    if (threadIdx.x == 0) {
        #pragma unroll
        for (int e = 0; e < NE; ++e) {
            float mx = fmaxf(fmaxf(sm[0][e], sm[1][e]), fmaxf(sm[2][e], sm[3][e]));
            gate[e] = (mx > THRESH) ? 1.f : 0.f;
        }
    }
}

// ---------------- expert conv + relu + gated combine -> img ----------------
// one block per patch; padded patch in LDS; wave wv owns co range; per-thread:
// pixel = lane, 8-co x 4-expert accumulator tile; weights are wave-uniform (scalar).
template<int CIN, int C, int CO>
__global__ __launch_bounds__(256) void expert_kernel(
    const float* __restrict__ X, const float* __restrict__ w2, const float* __restrict__ eb,
    const float* __restrict__ scores, const float* __restrict__ gate,
    float* __restrict__ img, int H, int W, int nP)
{
    __shared__ float pat[C * 100];  // C x 10 x 10, zero border
    const int P = nP * nP;
    const int bp = blockIdx.x;
    const int b = bp / P, pi = bp % P;
    const int py = pi / nP, px = pi % nP;
    const int tid = threadIdx.x;

    for (int i = tid; i < C * 100; i += 256) pat[i] = 0.f;
    __syncthreads();
    for (int i = tid; i < C * 64; i += 256) {
        int c = i >> 6, p = i & 63, h = p >> 3, w = p & 7;
        int gy = py * 8 + h, gx = px * 8 + w;
        float v;
        if (c < CIN) {
            v = X[(((size_t)b * CIN + c) * H + gy) * W + gx];
        } else {
            float t = (c == CIN || c == CIN + 2) ? gx * (1.f / (W - 1)) : gy * (1.f / (H - 1));
            v = (c >= CIN + 2) ? sinf(3.14159265358979323846f * t) : t;
        }
        pat[c * 100 + (h + 1) * 10 + (w + 1)] = v;
    }
    __syncthreads();

    float sg[NE];
    #pragma unroll
    for (int e = 0; e < NE; ++e) sg[e] = scores[bp * NE + e] * gate[e];

    const int pix = tid & 63, h = pix >> 3, w = pix & 7, wv = tid >> 6;
    const int y = py * 8 + h, x = px * 8 + w;
    const int CPW = CO / 4;           // co per wave
    const int EO = NE * CO;

    for (int co_t = 0; co_t < CPW; co_t += 8) {
        const int co0 = __builtin_amdgcn_readfirstlane(wv * CPW + co_t);
        float acc[NE][8];
        #pragma unroll
        for (int e = 0; e < NE; ++e)
            #pragma unroll
            for (int k = 0; k < 8; ++k) acc[e][k] = eb[e * CO + co0 + k];

        const int base = h * 10 + w;   // tap (i,j) at base + i*10 + j in a 10x10 plane
        for (int c = 0; c < C; ++c) {
            float n[9];
            #pragma unroll
            for (int i = 0; i < 3; ++i)
                #pragma unroll
                for (int j = 0; j < 3; ++j) n[i * 3 + j] = pat[c * 100 + base + i * 10 + j];
            const float* wc = w2 + (size_t)(c * 9) * EO + co0;
            #pragma unroll
            for (int ij = 0; ij < 9; ++ij) {
                const float nv = n[ij];
                const float* wr = wc + ij * EO;     // wave-uniform address
                #pragma unroll
                for (int e = 0; e < NE; ++e)
                    #pragma unroll
                    for (int k = 0; k < 8; ++k)
                        acc[e][k] = fmaf(wr[e * CO + k], nv, acc[e][k]);
            }
        }
        #pragma unroll
        for (int k = 0; k < 8; ++k) {
            float cv = 0.f;
            #pragma unroll
            for (int e = 0; e < NE; ++e) cv += sg[e] * fmaxf(acc[e][k], 0.f);
            img[(((size_t)b * CO + co0 + k) * H + y) * W + x] = cv;
        }
    }
}

// ---------------- fin: 1x1 conv with pad 4 (border = bias) ----------------
__global__ __launch_bounds__(128) void fin_kernel(
    const float* __restrict__ img, const float* __restrict__ fwT, const float* __restrict__ fb,
    float* __restrict__ Xn, int Co, int H, int W)
{
    const int Hout = H + 8, Wout = W + 8;
    const int nT = Co / 16;
    int bi = blockIdx.x;
    const int y = bi % Hout; bi /= Hout;
    const int ot = bi % nT;  const int b = bi / nT;
    const int o0 = ot * 16;
    const int x = threadIdx.x;
    if (x >= Wout) return;
    float acc[16];
    #pragma unroll
    for (int k = 0; k < 16; ++k) acc[k] = 0.f;
    if (y >= 4 && y < H + 4 && x >= 4 && x < W + 4) {
        for (int c = 0; c < Co; ++c) {
            float v = img[(((size_t)b * Co + c) * H + (y - 4)) * W + (x - 4)];
            #pragma unroll
            for (int k = 0; k < 16; ++k) acc[k] = fmaf(fwT[c * Co + o0 + k], v, acc[k]);
        }
    }
    #pragma unroll
    for (int k = 0; k < 16; ++k)
        Xn[(((size_t)b * Co + o0 + k) * Hout + y) * Wout + x] = acc[k] + fb[o0 + k];
}

// ---------------- final linear: (16, 128*96*96) @ (10, feat)^T + b ----------------
__global__ __launch_bounds__(256) void linear_kernel(
    const float* __restrict__ Xf, const float* __restrict__ lw, const float* __restrict__ lb,
    float* __restrict__ out)
{
    const int b = blockIdx.x / 10, o = blockIdx.x % 10;
    const int feat = 128 * 96 * 96;
    const float4* xa = (const float4*)(Xf + (size_t)b * feat);
    const float4* wa = (const float4*)(lw + (size_t)o * feat);
    float acc = 0.f;
    for (int i = threadIdx.x; i < feat / 4; i += 256) {
        float4 xv = xa[i], wv = wa[i];
        acc += xv.x * wv.x + xv.y * wv.y + xv.z * wv.z + xv.w * wv.w;
    }
    for (int m = 32; m; m >>= 1) acc += __shfl_xor(acc, m);
    __shared__ float sm[4];
    if ((threadIdx.x & 63) == 0) sm[threadIdx.x >> 6] = acc;
    __syncthreads();
    if (threadIdx.x == 0) out[blockIdx.x] = sm[0] + sm[1] + sm[2] + sm[3] + lb[o];
}

// ---------------- host driver ----------------
template<int CIN, int C, int CO>
static void run_layer(const float* Xin, int H, int nP, const float* const* Lw,
                      const float* rw, const float* rb,
                      float* w2, float* fwT, float* scores, float* gate,
                      float* img, float* Xn, hipStream_t stream)
{
    const int W = H;
    const int P = nP * nP;
    const int BP = NB * P;
    const int EO = NE * CO;
    const float* pw = Lw[0]; const float* pb = Lw[1];
    const float* ew = Lw[2]; const float* ebias = Lw[3];
    const float* fw = Lw[4]; const float* fb = Lw[5];

    repack_w_kernel<<<128, 256, 0, stream>>>(ew, w2, EO, C);
    repack_fin_kernel<<<(CO * CO + 255) / 256, 256, 0, stream>>>(fw, fwT, CO);
    router_kernel<CIN, C><<<BP / 4, 256, 0, stream>>>(Xin, pw, pb, rw, rb, scores, H, W, nP);
    gate_kernel<<<1, 256, 0, stream>>>(scores, BP, gate);
    expert_kernel<CIN, C, CO><<<BP, 256, 0, stream>>>(Xin, w2, ebias, scores, gate, img, H, W, nP);
    fin_kernel<<<NB * (CO / 16) * (H + 8), 128, 0, stream>>>(img, fwT, fb, Xn, CO, H, W);
}

extern "C" void kernel_launch(void* const* d_in, const int* in_sizes, int n_in,
                              void* d_out, int out_size, void* d_ws, size_t ws_size,
                              hipStream_t stream)
{
    const float* X0 = (const float*)d_in[0];
    const float* L[4][6];
    for (int l = 0; l < 4; ++l)
        for (int k = 0; k < 6; ++k) L[l][k] = (const float*)d_in[1 + l * 6 + k];
    const float* rw = (const float*)d_in[25];
    const float* rb = (const float*)d_in[26];
    const float* lw = (const float*)d_in[27];
    const float* lb = (const float*)d_in[28];

    // workspace layout (~141.5 MB total)
    char* ws = (char*)d_ws;
    const size_t IMG_B  = 63438848;   // 16*128*88*88*4  (max img)
    const size_t X_B    = 75497472;   // 16*128*96*96*4  (max X)
    const size_t W2_B   = 2433024;    // 512*132*9*4     (max repacked expert w)
    float* img    = (float*)(ws);
    float* bufX   = (float*)(ws + IMG_B);
    float* w2     = (float*)(ws + IMG_B + X_B);
    float* fwT    = (float*)(ws + IMG_B + X_B + W2_B);
    float* scores = fwT + 128 * 128;
    float* gate   = scores + 1936 * 4;

    // layer l: X (NB,CIN,H,H) -> img (NB,CO,H,H) -> X_next (NB,CO,H+8,H+8)
    run_layer<3,   7,   64>(X0,   64,  8, L[0], rw, rb, w2, fwT, scores, gate, img, bufX, stream);
    run_layer<64,  68,  64>(bufX, 72,  9, L[1], rw, rb, w2, fwT, scores, gate, img, bufX, stream);
    run_layer<64,  68, 128>(bufX, 80, 10, L[2], rw, rb, w2, fwT, scores, gate, img, bufX, stream);
    run_layer<128, 132, 128>(bufX, 88, 11, L[3], rw, rb, w2, fwT, scores, gate, img, bufX, stream);

    linear_kernel<<<160, 256, 0, stream>>>(bufX, lw, lb, (float*)d_out);
}